// Round 2
// baseline (664.038 us; speedup 1.0000x reference)
//
#include <hip/hip_runtime.h>

#define NF 64
#define NH 32
#define NK 16
#define NNODES 15
#define BLOCK 512

// W2 node stride padded so (stride % 32) == 4: the 8 distinct level-3 nodes
// land on disjoint 4-bank groups -> divergent ds_read_b128 is conflict-free.
#define W2_STRIDE 1028   // 32*32 = 1024 -> +4
#define SUB_STRIDE 17    // 16 -> +1

__global__ __launch_bounds__(BLOCK, 4) void tree_mlp_kernel(
    const float* __restrict__ x,
    const float* __restrict__ W1, const float* __restrict__ b1,
    const float* __restrict__ W2, const float* __restrict__ b2,
    const float* __restrict__ W3, const float* __restrict__ b3,
    const float* __restrict__ leaf_best, const int* __restrict__ subset_idx,
    float* __restrict__ out, int N)
{
    // Static shared, 62896 B total — under the 64 KiB/workgroup limit, so no
    // hipFuncSetAttribute / dynamic-LDS opt-in (that path broke graph replay in R1).
    __shared__ __align__(16) float W2L[NNODES * W2_STRIDE];   // 61680 B
    __shared__ int   subL[NNODES * SUB_STRIDE + 1];           // 1024 B
    __shared__ float b3L[32];                                 // 128 B
    __shared__ float leafL[16];                               // 64 B

    const int tid = threadIdx.x;

    // ---- Stage W2 + small tables into LDS (coalesced) ----
    for (int i = tid; i < NNODES * 1024; i += BLOCK)
        W2L[(i >> 10) * W2_STRIDE + (i & 1023)] = W2[i];
    for (int i = tid; i < NNODES * NK; i += BLOCK)
        subL[(i >> 4) * SUB_STRIDE + (i & 15)] = subset_idx[i];
    for (int i = tid; i < NNODES * 2; i += BLOCK) b3L[i] = b3[i];
    for (int i = tid; i < 16; i += BLOCK) leafL[i] = leaf_best[i];
    __syncthreads();

    const int s = blockIdx.x * BLOCK + tid;
    if (s >= N) return;

    const float* xr = x + (size_t)s * NF;

    int loc = 0, off = 0;
    #pragma unroll 1   // keep level loop rolled: avoid 4x I$ blowup of the ~1.6k-FMA body
    for (int level = 0; level < 4; ++level) {
        const int node = off + loc;

        // Gather the 16 subset features for this node (per-lane, L1/L2-served)
        float xs[NK];
        const int* si = subL + node * SUB_STRIDE;
        #pragma unroll
        for (int k = 0; k < NK; ++k) xs[k] = xr[si[k]];

        // h1 = leaky(W1[node] @ xs + b1[node])   (32x16 GEMV, W1 from global;
        // <=8 distinct nodes per wave -> TA dedup + L1 hits)
        float h1v[NH];
        const float* w1g = W1 + node * (NH * NK);
        const float* b1g = b1 + node * NH;
        #pragma unroll
        for (int j = 0; j < NH; ++j) {
            const float4* wr4 = (const float4*)(w1g + j * NK);  // 64B-aligned rows
            float w[NK];
            ((float4*)w)[0] = wr4[0];
            ((float4*)w)[1] = wr4[1];
            ((float4*)w)[2] = wr4[2];
            ((float4*)w)[3] = wr4[3];
            float acc = b1g[j];
            #pragma unroll
            for (int k = 0; k < NK; ++k) acc += w[k] * xs[k];   // same order as R1 (exact)
            h1v[j] = (acc >= 0.f) ? acc : 0.01f * acc;
        }

        // h2 = leaky(W2[node] @ h1 + b2[node])   (32x32 GEMV, W2 from LDS)
        float h2v[NH];
        const float* w2n = W2L + node * W2_STRIDE;
        const float* b2g = b2 + node * NH;
        #pragma unroll
        for (int g = 0; g < NH; ++g) {
            const float4* wr4 = (const float4*)(w2n + g * NH);  // 16B-aligned (1028*4, 128B rows)
            float w[NH];
            #pragma unroll
            for (int q = 0; q < 8; ++q) ((float4*)w)[q] = wr4[q];  // ds_read_b128 x8
            float acc = b2g[g];
            #pragma unroll
            for (int h = 0; h < NH; ++h) acc += w[h] * h1v[h];
            h2v[g] = (acc >= 0.f) ? acc : 0.01f * acc;
        }

        // logits; p0 < 0.5  <=>  l0 < l1  (softmax is monotone)
        const float* w3g = W3 + node * 2 * NH;
        float l0 = b3L[node * 2 + 0];
        float l1 = b3L[node * 2 + 1];
        #pragma unroll
        for (int h = 0; h < NH; ++h) {
            l0 += w3g[h]      * h2v[h];
            l1 += w3g[NH + h] * h2v[h];
        }

        const int bit = (l0 < l1) ? 1 : 0;
        loc = 2 * loc + bit;
        off = 2 * off + 1;   // node offsets: 0, 1, 3, 7
    }

    out[s] = leafL[loc];
}

extern "C" void kernel_launch(void* const* d_in, const int* in_sizes, int n_in,
                              void* d_out, int out_size, void* d_ws, size_t ws_size,
                              hipStream_t stream) {
    const float* x         = (const float*)d_in[0];
    const float* W1        = (const float*)d_in[1];
    const float* b1        = (const float*)d_in[2];
    const float* W2        = (const float*)d_in[3];
    const float* b2        = (const float*)d_in[4];
    const float* W3        = (const float*)d_in[5];
    const float* b3        = (const float*)d_in[6];
    const float* leaf_best = (const float*)d_in[7];
    const int*   subset    = (const int*)d_in[8];

    const int N = in_sizes[0] / NF;
    const int grid = (N + BLOCK - 1) / BLOCK;
    tree_mlp_kernel<<<grid, BLOCK, 0, stream>>>(
        x, W1, b1, W2, b2, W3, b3, leaf_best, subset, (float*)d_out, N);
}